// Round 7
// baseline (479.085 us; speedup 1.0000x reference)
//
#include <hip/hip_runtime.h>

#define HH 512
#define WW 512
#define BB 8
#define IMG (HH*WW)
#define NTOT (BB*IMG)

typedef float f32x4 __attribute__((ext_vector_type(4)));
typedef _Float16 half8 __attribute__((ext_vector_type(8)));

__device__ inline uint f2h2(float a, float b) {
  uint d; asm("v_cvt_pkrtz_f16_f32 %0, %1, %2" : "=v"(d) : "v"(a), "v"(b)); return d;
}
__device__ inline uint pkfma(uint a, uint b, uint c) {
  uint d; asm("v_pk_fma_f16 %0, %1, %2, %3" : "=v"(d) : "v"(a), "v"(b), "v"(c)); return d;
}
__device__ inline uint pkmax0(uint a) {
  uint d, z = 0u; asm("v_pk_max_f16 %0, %1, %2" : "=v"(d) : "v"(a), "v"(z)); return d;
}

__device__ inline void atomic_block_sum(float part, float* red, float* dst) {
  for (int off = 32; off > 0; off >>= 1) part += __shfl_down(part, off, 64);
  int lane = threadIdx.x & 63, w = threadIdx.x >> 6;
  if (lane == 0) red[w] = part;
  __syncthreads();
  if (threadIdx.x == 0) atomicAdd(dst, red[0] + red[1] + red[2] + red[3]);
}

// ---------------- prep: zero scalars, G stencil, fp16 weight packing ---------------
__global__ void k_prep(const float* __restrict__ Ka, const float* __restrict__ Kw,
                       const float* __restrict__ miu,
                       const float* __restrict__ W1, const float* __restrict__ b1,
                       const float* __restrict__ W2, const float* __restrict__ W3,
                       float* __restrict__ G, ushort* __restrict__ w2pk,
                       uint* __restrict__ w1pk, uint* __restrict__ b1pk,
                       ushort* __restrict__ w3fr, float* __restrict__ scal) {
  __shared__ float lka[25], lkw[36], lw1[288], lw3[288];
  int tid = threadIdx.x;
  if (tid < 192) scal[tid] = 0.f;
  if (tid < 25) lka[tid] = Ka[tid];
  if (tid < 36) lkw[tid] = Kw[tid];
  if (tid < 256) { lw1[tid] = W1[tid]; lw3[tid] = W3[tid]; }
  if (tid < 32) { lw1[256+tid] = W1[256+tid]; lw3[256+tid] = W3[256+tid]; }
  __syncthreads();
  if (tid < 81) {
    int oy = tid / 9 - 4, ox = tid % 9 - 4;
    float mu = miu[0];
    float ga = 0.f;
    for (int dy = 0; dy < 5; dy++)
      for (int dx = 0; dx < 5; dx++) {
        int ey = dy + oy, ex = dx + ox;
        if (ey >= 0 && ey < 5 && ex >= 0 && ex < 5) ga += lka[dy*5+dx] * lka[ey*5+ex];
      }
    float gw = 0.f;
    if (oy >= -2 && oy <= 2 && ox >= -2 && ox <= 2) {
      for (int ch = 0; ch < 4; ch++)
        for (int dy = 0; dy < 3; dy++)
          for (int dx = 0; dx < 3; dx++) {
            int ey = dy + oy, ex = dx + ox;
            if (ey >= 0 && ey < 3 && ex >= 0 && ex < 3)
              gw += lkw[ch*9 + dy*3+dx] * lkw[ch*9 + ey*3+ex];
          }
    }
    G[tid] = ga + mu * gw;
  }
  // W2 pack: constant trip count so loads overlap
  #pragma unroll 1
  for (int k = 0; k < 36; k++) {
    int i = tid + k*256;
    int j = i & 7, l = (i >> 3) & 63, f = i >> 9;
    int t5 = f >> 1, h = f & 1;
    int co = 16*h + (l & 15), ci = 8*(l >> 4) + j;
    w2pk[i] = (ushort)(f2h2(W2[(co*32 + ci)*9 + t5], 0.f) & 0xffffu);
  }
  if (tid < 144) {
    int cp = tid / 9, t = tid % 9;
    w1pk[tid] = f2h2(lw1[(2*cp)*9 + t], lw1[(2*cp+1)*9 + t]);
  }
  if (tid < 16) b1pk[tid] = f2h2(b1[2*tid], b1[2*tid+1]);
  for (int k = 0; k < 2; k++) {
    int i = tid + k*256;
    int j = i & 7, l = i >> 3;
    int tap = l & 15, ch = 8*(l >> 4) + j;
    w3fr[i] = (tap < 9) ? (ushort)(f2h2(lw3[ch*9 + tap], 0.f) & 0xffffu) : (ushort)0;
  }
}

// ---------------- fused CNN: xk = cnn(x), fp16/MFMA --------------------------------
// h1u: [row*356 + kg*88 + px*4 + cl] (row stride 356: +4 banks/row)
// h2u: [row*304 + slice*76 + px*4 + sub]
__launch_bounds__(512)
__global__ void k_cnn(const float* __restrict__ x,
                      const ushort* __restrict__ w2pk, const uint* __restrict__ w1pk,
                      const uint* __restrict__ b1pk, const ushort* __restrict__ w3fr,
                      const float* __restrict__ b2, const float* __restrict__ b3,
                      float* __restrict__ xk) {
  __shared__ __align__(16) uint  xs_h2[528];        // 22 rows x 24 cols, half2-bcast
  __shared__ __align__(16) uint  h1u[7120];         // 20 x 356
  __shared__ __align__(16) uint  h2u[5472];         // 18 x 304

  const int tid = threadIdx.x;
  const int bimg = blockIdx.z;
  const int oy0 = blockIdx.y * 16, ox0 = blockIdx.x * 16;
  const float* xim = x + (size_t)bimg * IMG;

  for (int i = tid; i < 528; i += 512) {
    int ly = i / 24, lx = i % 24;
    int gy = oy0 + ly - 3, gx = ox0 + lx - 4;
    float v = 0.f;
    if ((unsigned)gy < HH && (unsigned)gx < WW) v = xim[gy*WW + gx];
    xs_h2[i] = f2h2(v, v);
  }
  __syncthreads();

  // ---- conv1: wave = 16 chpairs x 4 consecutive rows (bank-minimal stores) ----
  {
    const int cp = tid & 15;
    const int sg = tid >> 4;          // 0..31
    uint w1r[9];
    #pragma unroll
    for (int k = 0; k < 9; k++) w1r[k] = w1pk[cp*9 + k];
    const uint b1v = b1pk[cp];
    const int kg = cp >> 2, cl = cp & 3;
    #pragma unroll 1
    for (int u = sg; u < 100; u += 32) {
      int quad = u >> 2, rw = u & 3;
      int st = quad % 5, rbase = (quad / 5) * 4;
      int row = rbase + rw;
      int px0 = st * 4;
      uint acc0 = b1v, acc1 = b1v, acc2 = b1v, acc3 = b1v;
      #pragma unroll
      for (int ky = 0; ky < 3; ky++) {
        int base = (row + ky) * 24 + px0;
        uint4 xa = *(const uint4*)&xs_h2[base];
        uint4 xb = *(const uint4*)&xs_h2[base + 4];
        uint xu[8] = {xa.x, xa.y, xa.z, xa.w, xb.x, xb.y, xb.z, xb.w};
        #pragma unroll
        for (int kx = 0; kx < 3; kx++) {
          uint w = w1r[ky*3 + kx];
          acc0 = pkfma(w, xu[1 + kx], acc0);
          acc1 = pkfma(w, xu[2 + kx], acc1);
          acc2 = pkfma(w, xu[3 + kx], acc2);
          acc3 = pkfma(w, xu[4 + kx], acc3);
        }
      }
      int Y = oy0 + row - 2;
      bool rin = (unsigned)Y < HH;
      int ob = row*356 + kg*88 + px0*4 + cl;
      #pragma unroll
      for (int i = 0; i < 4; i++) {
        int X = ox0 + px0 + i - 2;
        uint v = (rin && (unsigned)X < WW) ?
                 pkmax0(i == 0 ? acc0 : (i == 1 ? acc1 : (i == 2 ? acc2 : acc3))) : 0u;
        h1u[ob + i*4] = v;
      }
    }
  }
  __syncthreads();

  // ---- conv2 via MFMA f16 ----
  const int wv = tid >> 6, lane = tid & 63;
  const int nn = lane & 15, kg = lane >> 4;
  {
    half8 afr[9][2];
    #pragma unroll
    for (int t5 = 0; t5 < 9; t5++) {
      afr[t5][0] = ((const half8*)w2pk)[(t5*2 + 0)*64 + lane];
      afr[t5][1] = ((const half8*)w2pk)[(t5*2 + 1)*64 + lane];
    }
    float b2A[4], b2B[4];
    #pragma unroll
    for (int j = 0; j < 4; j++) { b2A[j] = b2[4*kg + j]; b2B[j] = b2[16 + 4*kg + j]; }

    #pragma unroll 1
    for (int t = wv; t < 27; t += 8) {
      int rp = t / 3, cs = t - 3*rp;
      int tx0 = (cs == 2) ? 10 : (cs << 3);
      int brow = 2*rp + (nn >> 3);
      int bcol = tx0 + (nn & 7);
      f32x4 accA = {0.f,0.f,0.f,0.f}, accB = {0.f,0.f,0.f,0.f};
      #pragma unroll
      for (int ky = 0; ky < 3; ky++)
        #pragma unroll
        for (int kx = 0; kx < 3; kx++) {
          const half8 bfr = *(const half8*)&h1u[(brow+ky)*356 + kg*88 + (bcol+kx)*4];
          accA = __builtin_amdgcn_mfma_f32_16x16x32_f16(afr[ky*3+kx][0], bfr, accA, 0, 0, 0);
          accB = __builtin_amdgcn_mfma_f32_16x16x32_f16(afr[ky*3+kx][1], bfr, accB, 0, 0, 0);
        }
      int gy = oy0 + brow - 1, gx = ox0 + bcol - 1;
      bool inb = ((unsigned)gy < HH) && ((unsigned)gx < WW);
      float v0 = inb ? fmaxf(accA[0] + b2A[0], 0.f) : 0.f;
      float v1 = inb ? fmaxf(accA[1] + b2A[1], 0.f) : 0.f;
      float v2 = inb ? fmaxf(accA[2] + b2A[2], 0.f) : 0.f;
      float v3 = inb ? fmaxf(accA[3] + b2A[3], 0.f) : 0.f;
      uint2 uA = make_uint2(f2h2(v0, v1), f2h2(v2, v3));
      v0 = inb ? fmaxf(accB[0] + b2B[0], 0.f) : 0.f;
      v1 = inb ? fmaxf(accB[1] + b2B[1], 0.f) : 0.f;
      v2 = inb ? fmaxf(accB[2] + b2B[2], 0.f) : 0.f;
      v3 = inb ? fmaxf(accB[3] + b2B[3], 0.f) : 0.f;
      uint2 uB = make_uint2(f2h2(v0, v1), f2h2(v2, v3));
      int base = brow*304 + bcol*4 + (kg & 1)*2;
      *(uint2*)&h2u[base + (kg >> 1)*76]       = uA;
      *(uint2*)&h2u[base + (2 + (kg >> 1))*76] = uB;
    }
  }
  __syncthreads();

  // ---- conv3 stage 1 via MFMA (Tlds aliased onto h1u, which is dead) ----
  float* Tlds = (float*)h1u;   // 3240 floats <= 7120 uints
  {
    const half8 w3f = ((const half8*)w3fr)[lane];
    const int tap = nn;
    #pragma unroll 1
    for (int t = wv; t < 27; t += 8) {
      int rp = t / 3, cs = t - 3*rp;
      int tx0 = (cs == 2) ? 10 : (cs << 3);
      int ay = 2*rp + (nn >> 3);
      int ax = tx0 + (nn & 7);
      const half8 afrag = *(const half8*)&h2u[ay*304 + kg*76 + ax*4];
      f32x4 z = {0.f,0.f,0.f,0.f};
      f32x4 T4 = __builtin_amdgcn_mfma_f32_16x16x32_f16(afrag, w3f, z, 0, 0, 0);
      if (tap < 9) {
        int ty = 2*rp + (kg >> 1);
        int txb = tx0 + 4*(kg & 1);
        float* dst = &Tlds[ty*180 + tap*20 + txb];
        if (cs == 2) {
          dst[0] = T4[0]; dst[1] = T4[1]; dst[2] = T4[2]; dst[3] = T4[3];
        } else {
          *(f32x4*)dst = T4;
        }
      }
    }
  }
  __syncthreads();

  // ---- conv3 gather + residual: all 512 threads (taps split 2-way + shfl) ----
  {
    const int half = tid & 1, px = tid >> 1;
    const int oy = px >> 4, ox = px & 15;
    float s = 0.f;
    if (half == 0) {
      #pragma unroll
      for (int t = 0; t < 4; t++)
        s += Tlds[(oy + t/3)*180 + t*20 + (ox + t%3)];
    } else {
      #pragma unroll
      for (int t = 4; t < 9; t++)
        s += Tlds[(oy + t/3)*180 + t*20 + (ox + t%3)];
    }
    float other = __shfl_xor(s, 1, 64);
    if (half == 0) {
      float tot = s + other + b3[0] + xim[(size_t)(oy0+oy)*WW + ox0 + ox];
      xk[(size_t)bimg*IMG + (size_t)(oy0+oy)*WW + ox0 + ox] = tot;
    }
  }
}

// ---------------- shared M-apply body ----------------------------------------------
__device__ __forceinline__ void apply_M(float (*ssrc)[76], float (*tbuf)[68],
    const float* Gs, const float* __restrict__ Ka, const float* __restrict__ Kw,
    float mu, bool edgeB, int tid, int oy0, int ox0, float* accv) {
  const int sy = tid >> 3, sx0 = (tid & 7) * 8;
  #pragma unroll
  for (int k = 0; k < 8; k++) accv[k] = 0.f;

  if (!edgeB) {
    #pragma unroll 1
    for (int oyy = 0; oyy < 9; oyy++) {
      float g[9];
      #pragma unroll
      for (int t = 0; t < 9; t++) g[t] = Gs[oyy*9+t];
      const float* row = &ssrc[sy+oyy][sx0];
      float4 r0 = *(const float4*)(row);
      float4 r1 = *(const float4*)(row+4);
      float4 r2 = *(const float4*)(row+8);
      float4 r3 = *(const float4*)(row+12);
      float v[16] = {r0.x,r0.y,r0.z,r0.w, r1.x,r1.y,r1.z,r1.w,
                     r2.x,r2.y,r2.z,r2.w, r3.x,r3.y,r3.z,r3.w};
      #pragma unroll
      for (int k = 0; k < 8; k++) {
        float a = accv[k];
        #pragma unroll
        for (int t = 0; t < 9; t++) a = fmaf(g[t], v[k+t], a);
        accv[k] = a;
      }
    }
  } else {
    {
      float ka[25];
      #pragma unroll
      for (int k = 0; k < 25; k++) ka[k] = Ka[k];
      #pragma unroll 1
      for (int item = tid; item < 324; item += 256) {
        int iy = item / 9, c = item - 9*iy;
        int x0 = c*8;
        float t[8];
        #pragma unroll
        for (int j = 0; j < 8; j++) t[j] = 0.f;
        #pragma unroll
        for (int dy = 0; dy < 5; dy++) {
          const float* row = &ssrc[iy+dy][x0];
          float4 r0 = *(const float4*)(row);
          float4 r1 = *(const float4*)(row+4);
          float4 r2 = *(const float4*)(row+8);
          float w[12] = {r0.x,r0.y,r0.z,r0.w, r1.x,r1.y,r1.z,r1.w, r2.x,r2.y,r2.z,r2.w};
          #pragma unroll
          for (int j = 0; j < 8; j++)
            #pragma unroll
            for (int dx = 0; dx < 5; dx++)
              t[j] = fmaf(ka[dy*5+dx], w[j+dx], t[j]);
        }
        int gy = oy0 + iy - 2;
        bool rin = (gy >= 0 && gy < HH);
        #pragma unroll
        for (int j = 0; j < 8; j++) {
          int ix = x0 + j;
          if (ix < 68) {
            int gx = ox0 + ix - 2;
            tbuf[iy][ix] = (rin && gx >= 0 && gx < WW) ? t[j] : 0.f;
          }
        }
      }
    }
    __syncthreads();
    {
      float ka[25];
      #pragma unroll
      for (int k = 0; k < 25; k++) ka[k] = Ka[k];
      #pragma unroll
      for (int dy = 0; dy < 5; dy++) {
        const float* row = &tbuf[sy+4-dy][sx0];
        float4 r0 = *(const float4*)(row);
        float4 r1 = *(const float4*)(row+4);
        float4 r2 = *(const float4*)(row+8);
        float w[12] = {r0.x,r0.y,r0.z,r0.w, r1.x,r1.y,r1.z,r1.w, r2.x,r2.y,r2.z,r2.w};
        #pragma unroll
        for (int k = 0; k < 8; k++)
          #pragma unroll
          for (int dx = 0; dx < 5; dx++)
            accv[k] = fmaf(ka[dy*5+dx], w[k+4-dx], accv[k]);
      }
    }
    __syncthreads();
    #pragma unroll 1
    for (int ch = 0; ch < 4; ch++) {
      {
        float kw[9];
        #pragma unroll
        for (int k = 0; k < 9; k++) kw[k] = Kw[ch*9 + k];
        #pragma unroll 1
        for (int item = tid; item < 306; item += 256) {
          int iy = item / 9, c = item - 9*iy;
          int x0 = c*8;
          float t[8];
          #pragma unroll
          for (int j = 0; j < 8; j++) t[j] = 0.f;
          #pragma unroll
          for (int dy = 0; dy < 3; dy++) {
            const float* row = &ssrc[iy+dy+2][x0];
            float4 r0 = *(const float4*)(row);
            float4 r1 = *(const float4*)(row+4);
            float4 r2 = *(const float4*)(row+8);
            float w[12] = {r0.x,r0.y,r0.z,r0.w, r1.x,r1.y,r1.z,r1.w, r2.x,r2.y,r2.z,r2.w};
            #pragma unroll
            for (int j = 0; j < 8; j++)
              #pragma unroll
              for (int dx = 0; dx < 3; dx++)
                t[j] = fmaf(kw[dy*3+dx], w[j+dx+2], t[j]);
          }
          int gy = oy0 + iy - 1;
          bool rin = (gy >= 0 && gy < HH);
          #pragma unroll
          for (int j = 0; j < 8; j++) {
            int ix = x0 + j;
            if (ix < 66) {
              int gx = ox0 + ix - 1;
              tbuf[iy][ix] = (rin && gx >= 0 && gx < WW) ? t[j] : 0.f;
            }
          }
        }
      }
      __syncthreads();
      {
        float kw[9];
        #pragma unroll
        for (int k = 0; k < 9; k++) kw[k] = mu * Kw[ch*9 + k];
        #pragma unroll
        for (int dy = 0; dy < 3; dy++) {
          const float* row = &tbuf[sy+2-dy][sx0];
          float4 r0 = *(const float4*)(row);
          float4 r1 = *(const float4*)(row+4);
          float4 r2 = *(const float4*)(row+8);
          float w[12] = {r0.x,r0.y,r0.z,r0.w, r1.x,r1.y,r1.z,r1.w, r2.x,r2.y,r2.z,r2.w};
          #pragma unroll
          for (int k = 0; k < 8; k++)
            #pragma unroll
            for (int dx = 0; dx < 3; dx++)
              accv[k] = fmaf(kw[dy*3+dx], w[k+2-dx], accv[k]);
        }
      }
      __syncthreads();
    }
  }
}

// ---------------- k_M0: fused rhs + r = M(xk) - rhs, p = -r, rtr reduction ---------
__launch_bounds__(256)
__global__ void k_M0(const float* __restrict__ xk, const float* __restrict__ sino,
                     const float* __restrict__ x,
                     float* __restrict__ outR, float* __restrict__ outP,
                     const float* __restrict__ G,
                     const float* __restrict__ Ka, const float* __restrict__ Kw,
                     const float* __restrict__ laam, const float* __restrict__ miu,
                     float* __restrict__ rtrOut) {
  __shared__ __align__(16) float ssrc[40][76];
  __shared__ __align__(16) float tbuf[36][68];
  __shared__ __align__(16) float ssin[36][68];
  __shared__ __align__(16) float sx[36][68];
  __shared__ float Gs[81], kas[25], kws[36];
  __shared__ float red[4];
  const int tid = threadIdx.x;
  const int bimg = blockIdx.z;
  const int oy0 = blockIdx.y*32, ox0 = blockIdx.x*64;
  const bool edgeB = (blockIdx.y == 0) || (blockIdx.y == gridDim.y-1) ||
                     (blockIdx.x == 0) || (blockIdx.x == gridDim.x-1);
  if (tid < 81) Gs[tid] = G[tid];
  if (tid >= 81 && tid < 106) kas[tid-81] = Ka[tid-81];
  if (tid >= 106 && tid < 142) kws[tid-106] = Kw[tid-106];
  const float mu = miu[0];
  const float lam = laam[0];
  const float* sxk = xk + (size_t)bimg*IMG;
  const float* ssi = sino + (size_t)bimg*IMG;
  const float* sxi = x + (size_t)bimg*IMG;

  for (int i = tid; i < 40*76; i += 256) {
    int ly = i/76, lx = i%76;
    int gy = oy0 + ly - 4, gx = ox0 + lx - 4;
    bool in = (lx < 72) && (gy >= 0 && gy < HH && gx >= 0 && gx < WW);
    ssrc[ly][lx] = in ? sxk[gy*WW+gx] : 0.f;
  }
  for (int i = tid; i < 36*68; i += 256) {
    int ly = i/68, lx = i%68;
    int gy = oy0 + ly - 2, gx = ox0 + lx - 2;
    bool in = (gy >= 0 && gy < HH && gx >= 0 && gx < WW);
    ssin[ly][lx] = in ? ssi[gy*WW+gx] : 0.f;
    sx[ly][lx]   = in ? sxi[gy*WW+gx] : 0.f;
  }
  __syncthreads();

  float accv[8];
  apply_M(ssrc, tbuf, Gs, kas, kws, mu, edgeB, tid, oy0, ox0, accv);

  const int sy = tid >> 3, sx0 = (tid & 7) * 8;
  // rhs: ATop(sino) part (single correlation, halo 2)
  float rhsv[8];
  #pragma unroll
  for (int k = 0; k < 8; k++) rhsv[k] = 0.f;
  {
    #pragma unroll
    for (int dy = 0; dy < 5; dy++) {
      const float* row = &ssin[sy+4-dy][sx0];
      float4 r0 = *(const float4*)(row);
      float4 r1 = *(const float4*)(row+4);
      float4 r2 = *(const float4*)(row+8);
      float w[12] = {r0.x,r0.y,r0.z,r0.w, r1.x,r1.y,r1.z,r1.w, r2.x,r2.y,r2.z,r2.w};
      #pragma unroll
      for (int k = 0; k < 8; k++)
        #pragma unroll
        for (int dx = 0; dx < 5; dx++)
          rhsv[k] = fmaf(kas[dy*5+dx], w[k+4-dx], rhsv[k]);
    }
  }
  // rhs: mu * WTop(softthresh(Wop(x))) part, per channel via tbuf
  #pragma unroll 1
  for (int ch = 0; ch < 4; ch++) {
    __syncthreads();   // prior tbuf readers done
    {
      float kw[9];
      #pragma unroll
      for (int k = 0; k < 9; k++) kw[k] = kws[ch*9 + k];
      #pragma unroll 1
      for (int item = tid; item < 2244; item += 256) {   // 34 x 66
        int dy = item / 66, dx = item - 66*dy;
        int gy = oy0 + dy - 1, gx = ox0 + dx - 1;
        float v = 0.f;
        if (gy >= 0 && gy < HH && gx >= 0 && gx < WW) {
          float wu = 0.f;
          #pragma unroll
          for (int e = 0; e < 9; e++) wu = fmaf(kw[e], sx[dy + e/3][dx + e%3], wu);
          v = fmaxf(wu - lam, 0.f) - fmaxf(-wu - lam, 0.f);
        }
        tbuf[dy][dx] = v;
      }
    }
    __syncthreads();
    {
      float kw[9];
      #pragma unroll
      for (int k = 0; k < 9; k++) kw[k] = mu * kws[ch*9 + k];
      #pragma unroll
      for (int dy = 0; dy < 3; dy++) {
        const float* row = &tbuf[sy+2-dy][sx0];
        float4 r0 = *(const float4*)(row);
        float4 r1 = *(const float4*)(row+4);
        float4 r2 = *(const float4*)(row+8);
        float w[12] = {r0.x,r0.y,r0.z,r0.w, r1.x,r1.y,r1.z,r1.w, r2.x,r2.y,r2.z,r2.w};
        #pragma unroll
        for (int k = 0; k < 8; k++)
          #pragma unroll
          for (int dx = 0; dx < 3; dx++)
            rhsv[k] = fmaf(kw[dy*3+dx], w[k+2-dx], rhsv[k]);
      }
    }
  }

  const int gy = oy0 + sy, gx0 = ox0 + sx0;
  float part = 0.f;
  #pragma unroll
  for (int k = 0; k < 8; k++) {
    size_t idx = (size_t)bimg*IMG + gy*WW + gx0 + k;
    float rv = accv[k] - rhsv[k];
    outR[idx] = rv;
    outP[idx] = -rv;
    part += rv*rv;
  }
  atomic_block_sum(part, red, &rtrOut[bimg]);
}

// ---------------- k_M: MODE 1 (q0 + den/rq/qq), MODE 2 (fallback) ------------------
template<int MODE>
__launch_bounds__(256)
__global__ void k_M(const float* __restrict__ srcA, const float* __restrict__ srcB,
                    float* __restrict__ outQ, float* __restrict__ outP,
                    const float* __restrict__ G,
                    const float* __restrict__ Ka, const float* __restrict__ Kw,
                    const float* __restrict__ miu,
                    const float* __restrict__ beN, const float* __restrict__ beD,
                    float* __restrict__ acc, float* __restrict__ rqOut,
                    float* __restrict__ qqOut) {
  __shared__ __align__(16) float ssrc[40][76];
  __shared__ __align__(16) float tbuf[36][68];
  __shared__ float Gs[81];
  __shared__ float red[12];
  const int tid = threadIdx.x;
  const int bimg = blockIdx.z;
  const int oy0 = blockIdx.y*32, ox0 = blockIdx.x*64;
  const bool edgeB = (blockIdx.y == 0) || (blockIdx.y == gridDim.y-1) ||
                     (blockIdx.x == 0) || (blockIdx.x == gridDim.x-1);
  if (tid < 81) Gs[tid] = G[tid];
  const float mu = miu[0];
  float be = 0.f;
  if (MODE == 2) be = beN[bimg] / beD[bimg];
  const float* sA = srcA + (size_t)bimg*IMG;
  const float* sB = (MODE == 2) ? srcB + (size_t)bimg*IMG : nullptr;

  for (int i = tid; i < 40*76; i += 256) {
    int ly = i/76, lx = i%76;
    int gy = oy0 + ly - 4, gx = ox0 + lx - 4;
    bool in = (lx < 72) && (gy >= 0 && gy < HH && gx >= 0 && gx < WW);
    float v = 0.f;
    if (MODE == 2) {
      if (in) {
        v = -sA[gy*WW+gx] + be * sB[gy*WW+gx];
        if (ly >= 4 && ly < 36 && lx >= 4 && lx < 68)
          outP[(size_t)bimg*IMG + gy*WW + gx] = v;
      }
    } else {
      if (in) v = sA[gy*WW+gx];
    }
    ssrc[ly][lx] = v;
  }
  __syncthreads();

  float accv[8];
  apply_M(ssrc, tbuf, Gs, Ka, Kw, mu, edgeB, tid, oy0, ox0, accv);

  const int sy = tid >> 3, sx0 = (tid & 7) * 8;
  const int gy = oy0 + sy, gx0 = ox0 + sx0;
  if (MODE == 1) {
    float pq = 0.f, qq = 0.f;
    #pragma unroll
    for (int k = 0; k < 8; k++) {
      size_t idx = (size_t)bimg*IMG + gy*WW + gx0 + k;
      float pv = ssrc[sy+4][sx0+4+k];
      float qv = accv[k];
      outQ[idx] = qv;
      pq += pv * qv;
      qq += qv * qv;
    }
    for (int off = 32; off > 0; off >>= 1) {
      pq += __shfl_down(pq, off, 64);
      qq += __shfl_down(qq, off, 64);
    }
    int lane = tid & 63, w = tid >> 6;
    if (lane == 0) { red[w*2] = pq; red[w*2+1] = qq; }
    __syncthreads();
    if (tid == 0) {
      float A = red[0]+red[2]+red[4]+red[6];
      float Q = red[1]+red[3]+red[5]+red[7];
      atomicAdd(&acc[bimg], A);
      if (rqOut) atomicAdd(&rqOut[bimg], -A);
      if (qqOut) atomicAdd(&qqOut[bimg], Q);
    }
  } else {
    float part = 0.f;
    #pragma unroll
    for (int k = 0; k < 8; k++) {
      size_t idx = (size_t)bimg*IMG + gy*WW + gx0 + k;
      float pv = ssrc[sy+4][sx0+4+k];
      outQ[idx] = accv[k];
      part += pv * accv[k];
    }
    atomic_block_sum(part, red, &acc[bimg]);
  }
}

// ---------------- fused CG iteration (scalar recurrence) ---------------------------
__launch_bounds__(256)
__global__ void k_it(float* __restrict__ xk,
                     const float* __restrict__ rold, float* __restrict__ rnew,
                     const float* __restrict__ pold, float* __restrict__ pnew,
                     const float* __restrict__ qold, float* __restrict__ qnew,
                     const float* __restrict__ G,
                     const float* __restrict__ Ka, const float* __restrict__ Kw,
                     const float* __restrict__ miu,
                     float* __restrict__ scal, int it, int storeQ) {
  __shared__ __align__(16) float ssrc[40][76];
  __shared__ __align__(16) float tbuf[36][68];
  __shared__ float rlds[2048];
  __shared__ float Gs[81];
  __shared__ float red[12];
  const int tid = threadIdx.x;
  const int bimg = blockIdx.z;
  const int oy0 = blockIdx.y*32, ox0 = blockIdx.x*64;
  const bool edgeB = (blockIdx.y == 0) || (blockIdx.y == gridDim.y-1) ||
                     (blockIdx.x == 0) || (blockIdx.x == gridDim.x-1);
  if (tid < 81) Gs[tid] = G[tid];
  const float mu = miu[0];
  const float den_p = scal[       (it-1)*8 + bimg];
  const float rq_p  = scal[ 48 + (it-1)*8 + bimg];
  const float qq_p  = scal[ 96 + (it-1)*8 + bimg];
  const float rtr_p = scal[144 + (it-1)*8 + bimg];
  const float al = rtr_p / den_p;
  const float rtr_c = fmaf(al, fmaf(al, qq_p, 2.f*rq_p), rtr_p);
  const float be = rtr_c / rtr_p;
  if (tid == 0) scal[144 + it*8 + bimg] = rtr_c;
  const size_t ib = (size_t)bimg*IMG;

  for (int i = tid; i < 40*76; i += 256) {
    int ly = i/76, lx = i%76;
    int gy = oy0 + ly - 4, gx = ox0 + lx - 4;
    bool in = (lx < 72) && (gy >= 0 && gy < HH && gx >= 0 && gx < WW);
    float v = 0.f;
    if (in) {
      size_t g = ib + (size_t)gy*WW + gx;
      float pg = pold[g];
      float rn = fmaf(al, qold[g], rold[g]);
      v = fmaf(be, pg, -rn);
      if (ly >= 4 && ly < 36 && lx >= 4 && lx < 68) {
        pnew[g] = v;
        rnew[g] = rn;
        xk[g] = fmaf(al, pg, xk[g]);
        rlds[(ly-4)*64 + (lx-4)] = rn;
      }
    }
    ssrc[ly][lx] = v;
  }
  __syncthreads();

  float accv[8];
  apply_M(ssrc, tbuf, Gs, Ka, Kw, mu, edgeB, tid, oy0, ox0, accv);

  const int sy = tid >> 3, sx0 = (tid & 7) * 8;
  const int gy = oy0 + sy, gx0 = ox0 + sx0;
  float s_den = 0.f, s_rq = 0.f, s_qq = 0.f;
  #pragma unroll
  for (int k = 0; k < 8; k++) {
    size_t idx = ib + (size_t)gy*WW + gx0 + k;
    float qv = accv[k];
    float pv = ssrc[sy+4][sx0+4+k];
    float rv = rlds[sy*64 + sx0 + k];
    if (storeQ) qnew[idx] = qv;
    s_den += pv*qv;
    s_rq  += rv*qv;
    s_qq  += qv*qv;
  }
  for (int off = 32; off > 0; off >>= 1) {
    s_den += __shfl_down(s_den, off, 64);
    s_rq  += __shfl_down(s_rq,  off, 64);
    s_qq  += __shfl_down(s_qq,  off, 64);
  }
  int lane = tid & 63, w = tid >> 6;
  if (lane == 0) { red[w*3] = s_den; red[w*3+1] = s_rq; red[w*3+2] = s_qq; }
  __syncthreads();
  if (tid == 0) {
    atomicAdd(&scal[       it*8 + bimg], red[0]+red[3]+red[6]+red[9]);
    atomicAdd(&scal[ 48 + it*8 + bimg], red[1]+red[4]+red[7]+red[10]);
    atomicAdd(&scal[ 96 + it*8 + bimg], red[2]+red[5]+red[8]+red[11]);
  }
}

// ---------------- fallback axpy ----------------------------------------------------
__launch_bounds__(256)
__global__ void k_upd(float* __restrict__ xk, float* __restrict__ r,
                      const float* __restrict__ p, const float* __restrict__ q,
                      const float* __restrict__ num, const float* __restrict__ den,
                      float* __restrict__ rtrOut) {
  __shared__ float red[4];
  const int tid = threadIdx.x;
  const int bimg = blockIdx.x >> 8;
  const size_t idx4 = (size_t)blockIdx.x * 256 + tid;
  const float al = num[bimg] / den[bimg];
  float4 xv = ((const float4*)xk)[idx4];
  float4 pv = ((const float4*)p)[idx4];
  float4 rv = ((const float4*)r)[idx4];
  float4 qv = ((const float4*)q)[idx4];
  xv.x += al*pv.x; xv.y += al*pv.y; xv.z += al*pv.z; xv.w += al*pv.w;
  rv.x += al*qv.x; rv.y += al*qv.y; rv.z += al*qv.z; rv.w += al*qv.w;
  ((float4*)xk)[idx4] = xv;
  ((float4*)r)[idx4] = rv;
  float part = rv.x*rv.x + rv.y*rv.y + rv.z*rv.z + rv.w*rv.w;
  atomic_block_sum(part, red, &rtrOut[bimg]);
}

__launch_bounds__(256)
__global__ void k_final(const float* __restrict__ xk, const float* __restrict__ p,
                        const float* __restrict__ num, const float* __restrict__ den,
                        float* __restrict__ out) {
  const int tid = threadIdx.x;
  const int bimg = blockIdx.x >> 8;
  const size_t idx4 = (size_t)blockIdx.x * 256 + tid;
  const float al = num[bimg] / den[bimg];
  float4 xv = ((const float4*)xk)[idx4];
  float4 pv = ((const float4*)p)[idx4];
  float4 o;
  o.x = xv.x + al*pv.x; o.y = xv.y + al*pv.y; o.z = xv.z + al*pv.z; o.w = xv.w + al*pv.w;
  ((float4*)out)[idx4] = o;
}

extern "C" void kernel_launch(void* const* d_in, const int* in_sizes, int n_in,
                              void* d_out, int out_size, void* d_ws, size_t ws_size,
                              hipStream_t stream) {
  const float* sino = (const float*)d_in[0];
  const float* x    = (const float*)d_in[1];
  const float* laam = (const float*)d_in[2];
  const float* miu  = (const float*)d_in[3];
  const float* Kw   = (const float*)d_in[4];
  const float* Ka   = (const float*)d_in[5];
  const float* W1   = (const float*)d_in[6];
  const float* b1   = (const float*)d_in[7];
  const float* W2   = (const float*)d_in[8];
  const float* b2   = (const float*)d_in[9];
  const float* W3   = (const float*)d_in[10];
  const float* b3   = (const float*)d_in[11];

  const bool fused = ws_size >= (size_t)6*NTOT*4 + 65536;
  float* ws = (float*)d_ws;
  const size_t nb = fused ? 6 : 5;
  float* tail = ws + nb*(size_t)NTOT;
  float* G    = tail;                  // 96
  float* scal = tail + 96;             // 192: den[48] rq[48] qq[48] rtr[48]
  ushort* w2pk = (ushort*)(scal + 192);
  uint*   w1pk = (uint*)(w2pk + 9216);
  uint*   b1pk = w1pk + 144;
  ushort* w3fr = (ushort*)(b1pk + 16);
  float* dout = (float*)d_out;

  k_prep<<<1, 256, 0, stream>>>(Ka, Kw, miu, W1, b1, W2, W3, G, w2pk, w1pk, b1pk,
                                w3fr, scal);

  float* xk = ws;
  k_cnn<<<dim3(32,32,8), 512, 0, stream>>>(x, w2pk, w1pk, b1pk, w3fr, b2, b3, xk);

  dim3 mg(8,16,8);
  if (fused) {
    float* rA = ws + (size_t)NTOT;
    float* rB = ws + 2*(size_t)NTOT;
    float* pA = ws + 3*(size_t)NTOT;
    float* pB = ws + 4*(size_t)NTOT;
    float* qB = ws + 5*(size_t)NTOT;
    float* qA = dout;
    k_M0<<<mg,256,0,stream>>>(xk, sino, x, rA, pA, G, Ka, Kw, laam, miu, &scal[144]);
    k_M<1><<<mg,256,0,stream>>>(pA, nullptr, qA, nullptr, G, Ka, Kw, miu,
                                nullptr, nullptr, &scal[0], &scal[48], &scal[96]);
    float *rc=rA, *rn=rB, *pc=pA, *pn=pB, *qc=qA, *qn=qB;
    for (int it = 1; it <= 5; it++) {
      k_it<<<mg,256,0,stream>>>(xk, rc, rn, pc, pn, qc, qn, G, Ka, Kw, miu, scal,
                                it, it < 5 ? 1 : 0);
      float* t;
      t = rc; rc = rn; rn = t;
      t = pc; pc = pn; pn = t;
      t = qc; qc = qn; qn = t;
    }
    k_final<<<2048,256,0,stream>>>(xk, pc, &scal[144+40], &scal[40], dout);
  } else {
    float* r  = ws + (size_t)NTOT;
    float* p0 = ws + 2*(size_t)NTOT;
    float* p1 = ws + 3*(size_t)NTOT;
    float* q  = ws + 4*(size_t)NTOT;
    k_M0<<<mg,256,0,stream>>>(xk, sino, x, r, p0, G, Ka, Kw, laam, miu, &scal[144]);
    k_M<1><<<mg,256,0,stream>>>(p0, nullptr, q, nullptr, G, Ka, Kw, miu,
                                nullptr, nullptr, &scal[0], nullptr, nullptr);
    k_upd<<<2048,256,0,stream>>>(xk, r, p0, q, &scal[144], &scal[0], &scal[144+8]);
    float* pcur = p0; float* pnext = p1;
    for (int i = 1; i <= 4; i++) {
      k_M<2><<<mg,256,0,stream>>>(r, pcur, q, pnext, G, Ka, Kw, miu,
                                  &scal[144+8*i], &scal[144+8*(i-1)], &scal[8*i],
                                  nullptr, nullptr);
      k_upd<<<2048,256,0,stream>>>(xk, r, pnext, q, &scal[144+8*i], &scal[8*i],
                                   &scal[144+8*(i+1)]);
      float* t = pcur; pcur = pnext; pnext = t;
    }
    k_M<2><<<mg,256,0,stream>>>(r, pcur, q, pnext, G, Ka, Kw, miu,
                                &scal[144+40], &scal[144+32], &scal[40],
                                nullptr, nullptr);
    k_final<<<2048,256,0,stream>>>(xk, pnext, &scal[144+40], &scal[40], dout);
  }
}

// Round 9
// 388.360 us; speedup vs baseline: 1.2336x; 1.2336x over previous
//
#include <hip/hip_runtime.h>

#define HH 512
#define WW 512
#define BB 8
#define IMG (HH*WW)
#define NTOT (BB*IMG)

typedef float f32x4 __attribute__((ext_vector_type(4)));
typedef _Float16 half8 __attribute__((ext_vector_type(8)));

__device__ inline uint f2h2(float a, float b) {
  uint d; asm("v_cvt_pkrtz_f16_f32 %0, %1, %2" : "=v"(d) : "v"(a), "v"(b)); return d;
}
__device__ inline uint pkfma(uint a, uint b, uint c) {
  uint d; asm("v_pk_fma_f16 %0, %1, %2, %3" : "=v"(d) : "v"(a), "v"(b), "v"(c)); return d;
}
__device__ inline uint pkmax0(uint a) {
  uint d, z = 0u; asm("v_pk_max_f16 %0, %1, %2" : "=v"(d) : "v"(a), "v"(z)); return d;
}

__device__ inline void atomic_block_sum(float part, float* red, float* dst) {
  for (int off = 32; off > 0; off >>= 1) part += __shfl_down(part, off, 64);
  int lane = threadIdx.x & 63, w = threadIdx.x >> 6;
  if (lane == 0) red[w] = part;
  __syncthreads();
  if (threadIdx.x == 0) atomicAdd(dst, red[0] + red[1] + red[2] + red[3]);
}

// ---------------- prep: zero scalars, G stencil, fp16 weight packing ---------------
__global__ void k_prep(const float* __restrict__ Ka, const float* __restrict__ Kw,
                       const float* __restrict__ miu,
                       const float* __restrict__ W1, const float* __restrict__ b1,
                       const float* __restrict__ W2, const float* __restrict__ W3,
                       float* __restrict__ G, ushort* __restrict__ w2pk,
                       uint* __restrict__ w1pk, uint* __restrict__ b1pk,
                       ushort* __restrict__ w3fr, float* __restrict__ scal) {
  __shared__ float lka[25], lkw[36], lw1[288], lw3[288];
  int tid = threadIdx.x;
  if (tid < 192) scal[tid] = 0.f;
  if (tid < 25) lka[tid] = Ka[tid];
  if (tid < 36) lkw[tid] = Kw[tid];
  if (tid < 256) { lw1[tid] = W1[tid]; lw3[tid] = W3[tid]; }
  if (tid < 32) { lw1[256+tid] = W1[256+tid]; lw3[256+tid] = W3[256+tid]; }
  __syncthreads();
  if (tid < 81) {
    int oy = tid / 9 - 4, ox = tid % 9 - 4;
    float mu = miu[0];
    float ga = 0.f;
    for (int dy = 0; dy < 5; dy++)
      for (int dx = 0; dx < 5; dx++) {
        int ey = dy + oy, ex = dx + ox;
        if (ey >= 0 && ey < 5 && ex >= 0 && ex < 5) ga += lka[dy*5+dx] * lka[ey*5+ex];
      }
    float gw = 0.f;
    if (oy >= -2 && oy <= 2 && ox >= -2 && ox <= 2) {
      for (int ch = 0; ch < 4; ch++)
        for (int dy = 0; dy < 3; dy++)
          for (int dx = 0; dx < 3; dx++) {
            int ey = dy + oy, ex = dx + ox;
            if (ey >= 0 && ey < 3 && ex >= 0 && ex < 3)
              gw += lkw[ch*9 + dy*3+dx] * lkw[ch*9 + ey*3+ex];
          }
    }
    G[tid] = ga + mu * gw;
  }
  #pragma unroll 1
  for (int k = 0; k < 36; k++) {
    int i = tid + k*256;
    int j = i & 7, l = (i >> 3) & 63, f = i >> 9;
    int t5 = f >> 1, h = f & 1;
    int co = 16*h + (l & 15), ci = 8*(l >> 4) + j;
    w2pk[i] = (ushort)(f2h2(W2[(co*32 + ci)*9 + t5], 0.f) & 0xffffu);
  }
  if (tid < 144) {
    int cp = tid / 9, t = tid % 9;
    w1pk[tid] = f2h2(lw1[(2*cp)*9 + t], lw1[(2*cp+1)*9 + t]);
  }
  if (tid < 16) b1pk[tid] = f2h2(b1[2*tid], b1[2*tid+1]);
  for (int k = 0; k < 2; k++) {
    int i = tid + k*256;
    int j = i & 7, l = i >> 3;
    int tap = l & 15, ch = 8*(l >> 4) + j;
    w3fr[i] = (tap < 9) ? (ushort)(f2h2(lw3[ch*9 + tap], 0.f) & 0xffffu) : (ushort)0;
  }
}

// ---------------- fused CNN: xk = cnn(x), fp16/MFMA --------------------------------
__launch_bounds__(512)
__global__ void k_cnn(const float* __restrict__ x,
                      const ushort* __restrict__ w2pk, const uint* __restrict__ w1pk,
                      const uint* __restrict__ b1pk, const ushort* __restrict__ w3fr,
                      const float* __restrict__ b2, const float* __restrict__ b3,
                      float* __restrict__ xk) {
  __shared__ __align__(16) uint  xs_h2[528];        // 22 rows x 24 cols, half2-bcast
  __shared__ __align__(16) uint  h1u[7040];         // 20 x 352
  __shared__ __align__(16) uint  h2u[5472];         // 18 x 304

  const int tid = threadIdx.x;
  const int bimg = blockIdx.z;
  const int oy0 = blockIdx.y * 16, ox0 = blockIdx.x * 16;
  const float* xim = x + (size_t)bimg * IMG;

  for (int i = tid; i < 528; i += 512) {
    int ly = i / 24, lx = i % 24;
    int gy = oy0 + ly - 3, gx = ox0 + lx - 4;
    float v = 0.f;
    if ((unsigned)gy < HH && (unsigned)gx < WW) v = xim[gy*WW + gx];
    xs_h2[i] = f2h2(v, v);
  }
  __syncthreads();

  // ---- conv1 ----
  {
    const int cp = tid & 15;
    const int sg = tid >> 4;
    uint w1r[9];
    #pragma unroll
    for (int k = 0; k < 9; k++) w1r[k] = w1pk[cp*9 + k];
    const uint b1v = b1pk[cp];
    const int kg = cp >> 2, cl = cp & 3;
    #pragma unroll 1
    for (int s = sg; s < 100; s += 32) {
      int row = s / 5, st = s - 5*row;
      int px0 = st * 4;
      uint acc0 = b1v, acc1 = b1v, acc2 = b1v, acc3 = b1v;
      #pragma unroll
      for (int ky = 0; ky < 3; ky++) {
        int base = (row + ky) * 24 + px0;
        uint4 xa = *(const uint4*)&xs_h2[base];
        uint4 xb = *(const uint4*)&xs_h2[base + 4];
        uint xu[8] = {xa.x, xa.y, xa.z, xa.w, xb.x, xb.y, xb.z, xb.w};
        #pragma unroll
        for (int kx = 0; kx < 3; kx++) {
          uint w = w1r[ky*3 + kx];
          acc0 = pkfma(w, xu[1 + kx], acc0);
          acc1 = pkfma(w, xu[2 + kx], acc1);
          acc2 = pkfma(w, xu[3 + kx], acc2);
          acc3 = pkfma(w, xu[4 + kx], acc3);
        }
      }
      int Y = oy0 + row - 2;
      bool rin = (unsigned)Y < HH;
      int ob = row*352 + kg*88 + px0*4 + cl;
      #pragma unroll
      for (int i = 0; i < 4; i++) {
        int X = ox0 + px0 + i - 2;
        uint v = (rin && (unsigned)X < WW) ?
                 pkmax0(i == 0 ? acc0 : (i == 1 ? acc1 : (i == 2 ? acc2 : acc3))) : 0u;
        h1u[ob + i*4] = v;
      }
    }
  }
  __syncthreads();

  // ---- conv2 via MFMA f16 ----
  const int wv = tid >> 6, lane = tid & 63;
  const int nn = lane & 15, kg = lane >> 4;
  {
    half8 afr[9][2];
    #pragma unroll
    for (int t5 = 0; t5 < 9; t5++) {
      afr[t5][0] = ((const half8*)w2pk)[(t5*2 + 0)*64 + lane];
      afr[t5][1] = ((const half8*)w2pk)[(t5*2 + 1)*64 + lane];
    }
    float b2A[4], b2B[4];
    #pragma unroll
    for (int j = 0; j < 4; j++) { b2A[j] = b2[4*kg + j]; b2B[j] = b2[16 + 4*kg + j]; }

    #pragma unroll 1
    for (int t = wv; t < 27; t += 8) {
      int rp = t / 3, cs = t - 3*rp;
      int tx0 = (cs == 2) ? 10 : (cs << 3);
      int brow = 2*rp + (nn >> 3);
      int bcol = tx0 + (nn & 7);
      f32x4 accA = {0.f,0.f,0.f,0.f}, accB = {0.f,0.f,0.f,0.f};
      #pragma unroll
      for (int ky = 0; ky < 3; ky++)
        #pragma unroll
        for (int kx = 0; kx < 3; kx++) {
          const half8 bfr = *(const half8*)&h1u[(brow+ky)*352 + kg*88 + (bcol+kx)*4];
          accA = __builtin_amdgcn_mfma_f32_16x16x32_f16(afr[ky*3+kx][0], bfr, accA, 0, 0, 0);
          accB = __builtin_amdgcn_mfma_f32_16x16x32_f16(afr[ky*3+kx][1], bfr, accB, 0, 0, 0);
        }
      int gy = oy0 + brow - 1, gx = ox0 + bcol - 1;
      bool inb = ((unsigned)gy < HH) && ((unsigned)gx < WW);
      float v0 = inb ? fmaxf(accA[0] + b2A[0], 0.f) : 0.f;
      float v1 = inb ? fmaxf(accA[1] + b2A[1], 0.f) : 0.f;
      float v2 = inb ? fmaxf(accA[2] + b2A[2], 0.f) : 0.f;
      float v3 = inb ? fmaxf(accA[3] + b2A[3], 0.f) : 0.f;
      uint2 uA = make_uint2(f2h2(v0, v1), f2h2(v2, v3));
      v0 = inb ? fmaxf(accB[0] + b2B[0], 0.f) : 0.f;
      v1 = inb ? fmaxf(accB[1] + b2B[1], 0.f) : 0.f;
      v2 = inb ? fmaxf(accB[2] + b2B[2], 0.f) : 0.f;
      v3 = inb ? fmaxf(accB[3] + b2B[3], 0.f) : 0.f;
      uint2 uB = make_uint2(f2h2(v0, v1), f2h2(v2, v3));
      int base = brow*304 + bcol*4 + (kg & 1)*2;
      *(uint2*)&h2u[base + (kg >> 1)*76]       = uA;
      *(uint2*)&h2u[base + (2 + (kg >> 1))*76] = uB;
    }
  }
  __syncthreads();

  // ---- conv3 stage 1 via MFMA (Tlds aliased onto dead h1u) ----
  float* Tlds = (float*)h1u;
  {
    const half8 w3f = ((const half8*)w3fr)[lane];
    const int tap = nn;
    #pragma unroll 1
    for (int t = wv; t < 27; t += 8) {
      int rp = t / 3, cs = t - 3*rp;
      int tx0 = (cs == 2) ? 10 : (cs << 3);
      int ay = 2*rp + (nn >> 3);
      int ax = tx0 + (nn & 7);
      const half8 afrag = *(const half8*)&h2u[ay*304 + kg*76 + ax*4];
      f32x4 z = {0.f,0.f,0.f,0.f};
      f32x4 T4 = __builtin_amdgcn_mfma_f32_16x16x32_f16(afrag, w3f, z, 0, 0, 0);
      if (tap < 9) {
        int ty = 2*rp + (kg >> 1);
        int txb = tx0 + 4*(kg & 1);
        float* dst = &Tlds[ty*180 + tap*20 + txb];
        if (cs == 2) {
          dst[0] = T4[0]; dst[1] = T4[1]; dst[2] = T4[2]; dst[3] = T4[3];
        } else {
          *(f32x4*)dst = T4;
        }
      }
    }
  }
  __syncthreads();

  // ---- conv3 gather + residual ----
  {
    const int half = tid & 1, px = tid >> 1;
    const int oy = px >> 4, ox = px & 15;
    float s = 0.f;
    if (half == 0) {
      #pragma unroll
      for (int t = 0; t < 4; t++)
        s += Tlds[(oy + t/3)*180 + t*20 + (ox + t%3)];
    } else {
      #pragma unroll
      for (int t = 4; t < 9; t++)
        s += Tlds[(oy + t/3)*180 + t*20 + (ox + t%3)];
    }
    float other = __shfl_xor(s, 1, 64);
    if (half == 0) {
      float tot = s + other + b3[0] + xim[(size_t)(oy0+oy)*WW + ox0 + ox];
      xk[(size_t)bimg*IMG + (size_t)(oy0+oy)*WW + ox0 + ox] = tot;
    }
  }
}

// ---------------- M-apply v2: G-stencil everywhere + exact band recompute ----------
__device__ __forceinline__ void apply_M2(const float (*ssrc)[76], float* bandv,
    const float* Gs, const float* __restrict__ Ka, const float* __restrict__ Kw,
    float mu, int tid, int oy0, int ox0, float* accv) {
  const int sy = tid >> 3, sx0 = (tid & 7) * 8;
  #pragma unroll
  for (int k = 0; k < 8; k++) accv[k] = 0.f;
  #pragma unroll 1
  for (int oyy = 0; oyy < 9; oyy++) {
    float g[9];
    #pragma unroll
    for (int t = 0; t < 9; t++) g[t] = Gs[oyy*9+t];
    const float* row = &ssrc[sy+oyy][sx0];
    float4 r0 = *(const float4*)(row);
    float4 r1 = *(const float4*)(row+4);
    float4 r2 = *(const float4*)(row+8);
    float4 r3 = *(const float4*)(row+12);
    float v[16] = {r0.x,r0.y,r0.z,r0.w, r1.x,r1.y,r1.z,r1.w,
                   r2.x,r2.y,r2.z,r2.w, r3.x,r3.y,r3.z,r3.w};
    #pragma unroll
    for (int k = 0; k < 8; k++) {
      float a = accv[k];
      #pragma unroll
      for (int t = 0; t < 9; t++) a = fmaf(g[t], v[k+t], a);
      accv[k] = a;
    }
  }
  // exact recompute within 2 px of image boundary (G is exact elsewhere)
  const int by = blockIdx.y, bx = blockIdx.x;
  const bool eT = (by == 0), eB = (by == (int)gridDim.y - 1);
  const bool eL = (bx == 0), eR = (bx == (int)gridDim.x - 1);
  if (eT | eB | eL | eR) {
    const int nTop = eT ? 128 : 0;
    const int nBot = eB ? 128 : 0;
    const int yl = eT ? 2 : 0, yh = eB ? 30 : 32;
    const int nL = eL ? 2*(yh-yl) : 0;
    const int nR = eR ? 2*(yh-yl) : 0;
    const int nBand = nTop + nBot + nL + nR;
    if (tid < nBand) {
      int i = tid, bsy, bsx;
      if (i < nTop) { bsy = i >> 6; bsx = i & 63; }
      else if (i < nTop + nBot) { i -= nTop; bsy = 30 + (i >> 6); bsx = i & 63; }
      else if (i < nTop + nBot + nL) { i -= nTop + nBot; bsy = yl + (i >> 1); bsx = i & 1; }
      else { i -= nTop + nBot + nL; bsy = yl + (i >> 1); bsx = 62 + (i & 1); }
      const int gy = oy0 + bsy, gx = ox0 + bsx;
      float P[9][9];
      #pragma unroll
      for (int r = 0; r < 9; r++)
        #pragma unroll
        for (int c = 0; c < 9; c++) P[r][c] = ssrc[bsy + r][bsx + c];
      float ka[25];
      #pragma unroll
      for (int k = 0; k < 25; k++) ka[k] = Ka[k];
      float qa = 0.f;
      #pragma unroll
      for (int dy = 0; dy < 5; dy++)
        #pragma unroll
        for (int dx = 0; dx < 5; dx++) {
          float inner = 0.f;
          #pragma unroll
          for (int ey = 0; ey < 5; ey++)
            #pragma unroll
            for (int ex = 0; ex < 5; ex++)
              inner = fmaf(ka[ey*5+ex], P[4+ey-dy][4+ex-dx], inner);
          bool ok = ((unsigned)(gy+2-dy) < HH) && ((unsigned)(gx+2-dx) < WW);
          qa = ok ? fmaf(ka[dy*5+dx], inner, qa) : qa;
        }
      float qw = 0.f;
      #pragma unroll
      for (int ch = 0; ch < 4; ch++) {
        float kw[9];
        #pragma unroll
        for (int k = 0; k < 9; k++) kw[k] = Kw[ch*9+k];
        #pragma unroll
        for (int dy = 0; dy < 3; dy++)
          #pragma unroll
          for (int dx = 0; dx < 3; dx++) {
            float inner = 0.f;
            #pragma unroll
            for (int ey = 0; ey < 3; ey++)
              #pragma unroll
              for (int ex = 0; ex < 3; ex++)
                inner = fmaf(kw[ey*3+ex], P[4+ey-dy][4+ex-dx], inner);
            bool ok = ((unsigned)(gy+1-dy) < HH) && ((unsigned)(gx+1-dx) < WW);
            qw = ok ? fmaf(kw[dy*3+dx], inner, qw) : qw;
          }
      }
      bandv[tid] = qa + mu * qw;
    }
    __syncthreads();
    #pragma unroll
    for (int k = 0; k < 8; k++) {
      const int sx = sx0 + k;
      const int gy = oy0 + sy, gx = ox0 + sx;
      if ((gy < 2) || (gy >= HH-2) || (gx < 2) || (gx >= WW-2)) {
        int idx;
        if (eT && sy < 2) idx = sy*64 + sx;
        else if (eB && sy >= 30) idx = nTop + (sy-30)*64 + sx;
        else if (eL && sx < 2) idx = nTop + nBot + (sy-yl)*2 + sx;
        else idx = nTop + nBot + nL + (sy-yl)*2 + (sx-62);
        accv[k] = bandv[idx];
      }
    }
  }
}

// ---------------- k_M0: fused rhs + r = M(xk) - rhs, p = -r, rtr reduction ---------
__launch_bounds__(256)
__global__ void k_M0(const float* __restrict__ xk, const float* __restrict__ sino,
                     const float* __restrict__ x,
                     float* __restrict__ outR, float* __restrict__ outP,
                     const float* __restrict__ G,
                     const float* __restrict__ Ka, const float* __restrict__ Kw,
                     const float* __restrict__ laam, const float* __restrict__ miu,
                     float* __restrict__ rtrOut) {
  __shared__ __align__(16) float ssrc[40][76];
  __shared__ __align__(16) float tbuf[36][68];     // also hosts bandv (first 256)
  __shared__ __align__(16) float ssin[36][68];
  __shared__ __align__(16) float sx[36][68];
  __shared__ float Gs[81], kas[25], kws[36];
  __shared__ float red[4];
  const int tid = threadIdx.x;
  const int bimg = blockIdx.z;
  const int oy0 = blockIdx.y*32, ox0 = blockIdx.x*64;
  if (tid < 81) Gs[tid] = G[tid];
  if (tid >= 81 && tid < 106) kas[tid-81] = Ka[tid-81];
  if (tid >= 106 && tid < 142) kws[tid-106] = Kw[tid-106];
  const float mu = miu[0];
  const float lam = laam[0];
  const float* sxk = xk + (size_t)bimg*IMG;
  const float* ssi = sino + (size_t)bimg*IMG;
  const float* sxi = x + (size_t)bimg*IMG;

  for (int i = tid; i < 40*76; i += 256) {
    int ly = i/76, lx = i%76;
    int gy = oy0 + ly - 4, gx = ox0 + lx - 4;
    bool in = (lx < 72) && (gy >= 0 && gy < HH && gx >= 0 && gx < WW);
    ssrc[ly][lx] = in ? sxk[gy*WW+gx] : 0.f;
  }
  for (int i = tid; i < 36*68; i += 256) {
    int ly = i/68, lx = i%68;
    int gy = oy0 + ly - 2, gx = ox0 + lx - 2;
    bool in = (gy >= 0 && gy < HH && gx >= 0 && gx < WW);
    ssin[ly][lx] = in ? ssi[gy*WW+gx] : 0.f;
    sx[ly][lx]   = in ? sxi[gy*WW+gx] : 0.f;
  }
  __syncthreads();

  float accv[8];
  apply_M2(ssrc, &tbuf[0][0], Gs, kas, kws, mu, tid, oy0, ox0, accv);

  const int sy = tid >> 3, sx0 = (tid & 7) * 8;
  float rhsv[8];
  #pragma unroll
  for (int k = 0; k < 8; k++) rhsv[k] = 0.f;
  {
    #pragma unroll
    for (int dy = 0; dy < 5; dy++) {
      const float* row = &ssin[sy+4-dy][sx0];
      float4 r0 = *(const float4*)(row);
      float4 r1 = *(const float4*)(row+4);
      float4 r2 = *(const float4*)(row+8);
      float w[12] = {r0.x,r0.y,r0.z,r0.w, r1.x,r1.y,r1.z,r1.w, r2.x,r2.y,r2.z,r2.w};
      #pragma unroll
      for (int k = 0; k < 8; k++)
        #pragma unroll
        for (int dx = 0; dx < 5; dx++)
          rhsv[k] = fmaf(kas[dy*5+dx], w[k+4-dx], rhsv[k]);
    }
  }
  #pragma unroll 1
  for (int ch = 0; ch < 4; ch++) {
    __syncthreads();
    {
      float kw[9];
      #pragma unroll
      for (int k = 0; k < 9; k++) kw[k] = kws[ch*9 + k];
      #pragma unroll 1
      for (int item = tid; item < 2244; item += 256) {   // 34 x 66
        int dy = item / 66, dx = item - 66*dy;
        int gy = oy0 + dy - 1, gx = ox0 + dx - 1;
        float v = 0.f;
        if (gy >= 0 && gy < HH && gx >= 0 && gx < WW) {
          float wu = 0.f;
          #pragma unroll
          for (int e = 0; e < 9; e++) wu = fmaf(kw[e], sx[dy + e/3][dx + e%3], wu);
          v = fmaxf(wu - lam, 0.f) - fmaxf(-wu - lam, 0.f);
        }
        tbuf[dy][dx] = v;
      }
    }
    __syncthreads();
    {
      float kw[9];
      #pragma unroll
      for (int k = 0; k < 9; k++) kw[k] = mu * kws[ch*9 + k];
      #pragma unroll
      for (int dy = 0; dy < 3; dy++) {
        const float* row = &tbuf[sy+2-dy][sx0];
        float4 r0 = *(const float4*)(row);
        float4 r1 = *(const float4*)(row+4);
        float4 r2 = *(const float4*)(row+8);
        float w[12] = {r0.x,r0.y,r0.z,r0.w, r1.x,r1.y,r1.z,r1.w, r2.x,r2.y,r2.z,r2.w};
        #pragma unroll
        for (int k = 0; k < 8; k++)
          #pragma unroll
          for (int dx = 0; dx < 3; dx++)
            rhsv[k] = fmaf(kw[dy*3+dx], w[k+2-dx], rhsv[k]);
      }
    }
  }

  const int gy = oy0 + sy, gx0 = ox0 + sx0;
  float part = 0.f;
  #pragma unroll
  for (int k = 0; k < 8; k++) {
    size_t idx = (size_t)bimg*IMG + gy*WW + gx0 + k;
    float rv = accv[k] - rhsv[k];
    outR[idx] = rv;
    outP[idx] = -rv;
    part += rv*rv;
  }
  atomic_block_sum(part, red, &rtrOut[bimg]);
}

// ---------------- k_M: MODE 1 (q0 + den/rq/qq), MODE 2 (fallback) ------------------
template<int MODE>
__launch_bounds__(256)
__global__ void k_M(const float* __restrict__ srcA, const float* __restrict__ srcB,
                    float* __restrict__ outQ, float* __restrict__ outP,
                    const float* __restrict__ G,
                    const float* __restrict__ Ka, const float* __restrict__ Kw,
                    const float* __restrict__ miu,
                    const float* __restrict__ beN, const float* __restrict__ beD,
                    float* __restrict__ acc, float* __restrict__ rqOut,
                    float* __restrict__ qqOut) {
  __shared__ __align__(16) float ssrc[40][76];
  __shared__ float bandv[256];
  __shared__ float Gs[81];
  __shared__ float red[12];
  const int tid = threadIdx.x;
  const int bimg = blockIdx.z;
  const int oy0 = blockIdx.y*32, ox0 = blockIdx.x*64;
  if (tid < 81) Gs[tid] = G[tid];
  const float mu = miu[0];
  float be = 0.f;
  if (MODE == 2) be = beN[bimg] / beD[bimg];
  const float* sA = srcA + (size_t)bimg*IMG;
  const float* sB = (MODE == 2) ? srcB + (size_t)bimg*IMG : nullptr;

  for (int i = tid; i < 40*76; i += 256) {
    int ly = i/76, lx = i%76;
    int gy = oy0 + ly - 4, gx = ox0 + lx - 4;
    bool in = (lx < 72) && (gy >= 0 && gy < HH && gx >= 0 && gx < WW);
    float v = 0.f;
    if (MODE == 2) {
      if (in) {
        v = -sA[gy*WW+gx] + be * sB[gy*WW+gx];
        if (ly >= 4 && ly < 36 && lx >= 4 && lx < 68)
          outP[(size_t)bimg*IMG + gy*WW + gx] = v;
      }
    } else {
      if (in) v = sA[gy*WW+gx];
    }
    ssrc[ly][lx] = v;
  }
  __syncthreads();

  float accv[8];
  apply_M2(ssrc, bandv, Gs, Ka, Kw, mu, tid, oy0, ox0, accv);

  const int sy = tid >> 3, sx0 = (tid & 7) * 8;
  const int gy = oy0 + sy, gx0 = ox0 + sx0;
  if (MODE == 1) {
    float pq = 0.f, qq = 0.f;
    #pragma unroll
    for (int k = 0; k < 8; k++) {
      size_t idx = (size_t)bimg*IMG + gy*WW + gx0 + k;
      float pv = ssrc[sy+4][sx0+4+k];
      float qv = accv[k];
      outQ[idx] = qv;
      pq += pv * qv;
      qq += qv * qv;
    }
    for (int off = 32; off > 0; off >>= 1) {
      pq += __shfl_down(pq, off, 64);
      qq += __shfl_down(qq, off, 64);
    }
    int lane = tid & 63, w = tid >> 6;
    if (lane == 0) { red[w*2] = pq; red[w*2+1] = qq; }
    __syncthreads();
    if (tid == 0) {
      float A = red[0]+red[2]+red[4]+red[6];
      float Q = red[1]+red[3]+red[5]+red[7];
      atomicAdd(&acc[bimg], A);
      if (rqOut) atomicAdd(&rqOut[bimg], -A);
      if (qqOut) atomicAdd(&qqOut[bimg], Q);
    }
  } else {
    float part = 0.f;
    #pragma unroll
    for (int k = 0; k < 8; k++) {
      size_t idx = (size_t)bimg*IMG + gy*WW + gx0 + k;
      float pv = ssrc[sy+4][sx0+4+k];
      outQ[idx] = accv[k];
      part += pv * accv[k];
    }
    atomic_block_sum(part, red, &acc[bimg]);
  }
}

// ---------------- fused CG iteration (scalar recurrence) ---------------------------
__launch_bounds__(256)
__global__ void k_it(float* __restrict__ xk,
                     const float* __restrict__ rold, float* __restrict__ rnew,
                     const float* __restrict__ pold, float* __restrict__ pnew,
                     const float* __restrict__ qold, float* __restrict__ qnew,
                     const float* __restrict__ G,
                     const float* __restrict__ Ka, const float* __restrict__ Kw,
                     const float* __restrict__ miu,
                     float* __restrict__ scal, int it, int storeQ) {
  __shared__ __align__(16) float ssrc[40][76];
  __shared__ float rlds[2048];
  __shared__ float bandv[256];
  __shared__ float Gs[81];
  __shared__ float red[12];
  const int tid = threadIdx.x;
  const int bimg = blockIdx.z;
  const int oy0 = blockIdx.y*32, ox0 = blockIdx.x*64;
  if (tid < 81) Gs[tid] = G[tid];
  const float mu = miu[0];
  const float den_p = scal[       (it-1)*8 + bimg];
  const float rq_p  = scal[ 48 + (it-1)*8 + bimg];
  const float qq_p  = scal[ 96 + (it-1)*8 + bimg];
  const float rtr_p = scal[144 + (it-1)*8 + bimg];
  const float al = rtr_p / den_p;
  const float rtr_c = fmaf(al, fmaf(al, qq_p, 2.f*rq_p), rtr_p);
  const float be = rtr_c / rtr_p;
  if (tid == 0) scal[144 + it*8 + bimg] = rtr_c;
  const size_t ib = (size_t)bimg*IMG;

  for (int i = tid; i < 40*76; i += 256) {
    int ly = i/76, lx = i%76;
    int gy = oy0 + ly - 4, gx = ox0 + lx - 4;
    bool in = (lx < 72) && (gy >= 0 && gy < HH && gx >= 0 && gx < WW);
    float v = 0.f;
    if (in) {
      size_t g = ib + (size_t)gy*WW + gx;
      float pg = pold[g];
      float rn = fmaf(al, qold[g], rold[g]);
      v = fmaf(be, pg, -rn);
      if (ly >= 4 && ly < 36 && lx >= 4 && lx < 68) {
        pnew[g] = v;
        rnew[g] = rn;
        xk[g] = fmaf(al, pg, xk[g]);
        rlds[(ly-4)*64 + (lx-4)] = rn;
      }
    }
    ssrc[ly][lx] = v;
  }
  __syncthreads();

  float accv[8];
  apply_M2(ssrc, bandv, Gs, Ka, Kw, mu, tid, oy0, ox0, accv);

  const int sy = tid >> 3, sx0 = (tid & 7) * 8;
  const int gy = oy0 + sy, gx0 = ox0 + sx0;
  float s_den = 0.f, s_rq = 0.f, s_qq = 0.f;
  #pragma unroll
  for (int k = 0; k < 8; k++) {
    size_t idx = ib + (size_t)gy*WW + gx0 + k;
    float qv = accv[k];
    float pv = ssrc[sy+4][sx0+4+k];
    float rv = rlds[sy*64 + sx0 + k];
    if (storeQ) qnew[idx] = qv;
    s_den += pv*qv;
    s_rq  += rv*qv;
    s_qq  += qv*qv;
  }
  for (int off = 32; off > 0; off >>= 1) {
    s_den += __shfl_down(s_den, off, 64);
    s_rq  += __shfl_down(s_rq,  off, 64);
    s_qq  += __shfl_down(s_qq,  off, 64);
  }
  int lane = tid & 63, w = tid >> 6;
  if (lane == 0) { red[w*3] = s_den; red[w*3+1] = s_rq; red[w*3+2] = s_qq; }
  __syncthreads();
  if (tid == 0) {
    atomicAdd(&scal[       it*8 + bimg], red[0]+red[3]+red[6]+red[9]);
    atomicAdd(&scal[ 48 + it*8 + bimg], red[1]+red[4]+red[7]+red[10]);
    atomicAdd(&scal[ 96 + it*8 + bimg], red[2]+red[5]+red[8]+red[11]);
  }
}

// ---------------- fallback axpy ----------------------------------------------------
__launch_bounds__(256)
__global__ void k_upd(float* __restrict__ xk, float* __restrict__ r,
                      const float* __restrict__ p, const float* __restrict__ q,
                      const float* __restrict__ num, const float* __restrict__ den,
                      float* __restrict__ rtrOut) {
  __shared__ float red[4];
  const int tid = threadIdx.x;
  const int bimg = blockIdx.x >> 8;
  const size_t idx4 = (size_t)blockIdx.x * 256 + tid;
  const float al = num[bimg] / den[bimg];
  float4 xv = ((const float4*)xk)[idx4];
  float4 pv = ((const float4*)p)[idx4];
  float4 rv = ((const float4*)r)[idx4];
  float4 qv = ((const float4*)q)[idx4];
  xv.x += al*pv.x; xv.y += al*pv.y; xv.z += al*pv.z; xv.w += al*pv.w;
  rv.x += al*qv.x; rv.y += al*qv.y; rv.z += al*qv.z; rv.w += al*qv.w;
  ((float4*)xk)[idx4] = xv;
  ((float4*)r)[idx4] = rv;
  float part = rv.x*rv.x + rv.y*rv.y + rv.z*rv.z + rv.w*rv.w;
  atomic_block_sum(part, red, &rtrOut[bimg]);
}

__launch_bounds__(256)
__global__ void k_final(const float* __restrict__ xk, const float* __restrict__ p,
                        const float* __restrict__ num, const float* __restrict__ den,
                        float* __restrict__ out) {
  const int tid = threadIdx.x;
  const int bimg = blockIdx.x >> 8;
  const size_t idx4 = (size_t)blockIdx.x * 256 + tid;
  const float al = num[bimg] / den[bimg];
  float4 xv = ((const float4*)xk)[idx4];
  float4 pv = ((const float4*)p)[idx4];
  float4 o;
  o.x = xv.x + al*pv.x; o.y = xv.y + al*pv.y; o.z = xv.z + al*pv.z; o.w = xv.w + al*pv.w;
  ((float4*)out)[idx4] = o;
}

extern "C" void kernel_launch(void* const* d_in, const int* in_sizes, int n_in,
                              void* d_out, int out_size, void* d_ws, size_t ws_size,
                              hipStream_t stream) {
  const float* sino = (const float*)d_in[0];
  const float* x    = (const float*)d_in[1];
  const float* laam = (const float*)d_in[2];
  const float* miu  = (const float*)d_in[3];
  const float* Kw   = (const float*)d_in[4];
  const float* Ka   = (const float*)d_in[5];
  const float* W1   = (const float*)d_in[6];
  const float* b1   = (const float*)d_in[7];
  const float* W2   = (const float*)d_in[8];
  const float* b2   = (const float*)d_in[9];
  const float* W3   = (const float*)d_in[10];
  const float* b3   = (const float*)d_in[11];

  const bool fused = ws_size >= (size_t)6*NTOT*4 + 65536;
  float* ws = (float*)d_ws;
  const size_t nb = fused ? 6 : 5;
  float* tail = ws + nb*(size_t)NTOT;
  float* G    = tail;
  float* scal = tail + 96;
  ushort* w2pk = (ushort*)(scal + 192);
  uint*   w1pk = (uint*)(w2pk + 9216);
  uint*   b1pk = w1pk + 144;
  ushort* w3fr = (ushort*)(b1pk + 16);
  float* dout = (float*)d_out;

  k_prep<<<1, 256, 0, stream>>>(Ka, Kw, miu, W1, b1, W2, W3, G, w2pk, w1pk, b1pk,
                                w3fr, scal);

  float* xk = ws;
  k_cnn<<<dim3(32,32,8), 512, 0, stream>>>(x, w2pk, w1pk, b1pk, w3fr, b2, b3, xk);

  dim3 mg(8,16,8);
  if (fused) {
    float* rA = ws + (size_t)NTOT;
    float* rB = ws + 2*(size_t)NTOT;
    float* pA = ws + 3*(size_t)NTOT;
    float* pB = ws + 4*(size_t)NTOT;
    float* qB = ws + 5*(size_t)NTOT;
    float* qA = dout;
    k_M0<<<mg,256,0,stream>>>(xk, sino, x, rA, pA, G, Ka, Kw, laam, miu, &scal[144]);
    k_M<1><<<mg,256,0,stream>>>(pA, nullptr, qA, nullptr, G, Ka, Kw, miu,
                                nullptr, nullptr, &scal[0], &scal[48], &scal[96]);
    float *rc=rA, *rn=rB, *pc=pA, *pn=pB, *qc=qA, *qn=qB;
    for (int it = 1; it <= 5; it++) {
      k_it<<<mg,256,0,stream>>>(xk, rc, rn, pc, pn, qc, qn, G, Ka, Kw, miu, scal,
                                it, it < 5 ? 1 : 0);
      float* t;
      t = rc; rc = rn; rn = t;
      t = pc; pc = pn; pn = t;
      t = qc; qc = qn; qn = t;
    }
    k_final<<<2048,256,0,stream>>>(xk, pc, &scal[144+40], &scal[40], dout);
  } else {
    float* r  = ws + (size_t)NTOT;
    float* p0 = ws + 2*(size_t)NTOT;
    float* p1 = ws + 3*(size_t)NTOT;
    float* q  = ws + 4*(size_t)NTOT;
    k_M0<<<mg,256,0,stream>>>(xk, sino, x, r, p0, G, Ka, Kw, laam, miu, &scal[144]);
    k_M<1><<<mg,256,0,stream>>>(p0, nullptr, q, nullptr, G, Ka, Kw, miu,
                                nullptr, nullptr, &scal[0], nullptr, nullptr);
    k_upd<<<2048,256,0,stream>>>(xk, r, p0, q, &scal[144], &scal[0], &scal[144+8]);
    float* pcur = p0; float* pnext = p1;
    for (int i = 1; i <= 4; i++) {
      k_M<2><<<mg,256,0,stream>>>(r, pcur, q, pnext, G, Ka, Kw, miu,
                                  &scal[144+8*i], &scal[144+8*(i-1)], &scal[8*i],
                                  nullptr, nullptr);
      k_upd<<<2048,256,0,stream>>>(xk, r, pnext, q, &scal[144+8*i], &scal[8*i],
                                   &scal[144+8*(i+1)]);
      float* t = pcur; pcur = pnext; pnext = t;
    }
    k_M<2><<<mg,256,0,stream>>>(r, pcur, q, pnext, G, Ka, Kw, miu,
                                &scal[144+40], &scal[144+32], &scal[40],
                                nullptr, nullptr);
    k_final<<<2048,256,0,stream>>>(xk, pnext, &scal[144+40], &scal[40], dout);
  }
}